// Round 4
// baseline (652.903 us; speedup 1.0000x reference)
//
#include <hip/hip_runtime.h>

// MoE expert FFN: T=256, E=16, H=2048, I=1024, top_k=4 (int32 device scalar).
// Inputs fp32, output fp32 (established R1-R3). Compute: bf16 MFMA.
//
// R4 change: latency-bound fix. R3 had 256 blocks = 1 block/CU = 1 wave/SIMD
// (OccupancyPercent 11%, 733 GB/s). Now each block owns ONE 16-wide n-tile and
// its 4 waves split the m-tiles (same weight rows -> L1-shared), giving
// gemm1 1024 blocks / gemm2 2048 blocks -> 16-32 waves/CU.

typedef __attribute__((ext_vector_type(8))) short bf16x8;   // MFMA A/B frag
typedef __attribute__((ext_vector_type(4))) float floatx4;  // MFMA C/D frag

#define T_TOK 256
#define N_EXP 16
#define H_DIM 2048
#define I_DIM 1024
#define MAX_SLOTS 256

__device__ __forceinline__ short f2bf(float f) {           // RNE fp32->bf16
    union { float f; unsigned u; } v; v.f = f;
    unsigned r = (v.u + 0x7FFFu + ((v.u >> 16) & 1u)) >> 16;
    return (short)r;
}
__device__ __forceinline__ float bf2f(short s) {
    union { unsigned u; float f; } v; v.u = ((unsigned)(unsigned short)s) << 16;
    return v.f;
}
__device__ __forceinline__ bf16x8 pack8(const float* __restrict__ p) {  // 8 fp32 -> bf16
    float4 a = *(const float4*)p, b = *(const float4*)(p + 4);
    bf16x8 r;
    r[0] = f2bf(a.x); r[1] = f2bf(a.y); r[2] = f2bf(a.z); r[3] = f2bf(a.w);
    r[4] = f2bf(b.x); r[5] = f2bf(b.y); r[6] = f2bf(b.z); r[7] = f2bf(b.w);
    return r;
}

// ---------------- x fp32 -> bf16 ----------------
__global__ __launch_bounds__(256) void convert_x_kernel(
    const float* __restrict__ xf, short* __restrict__ xb)
{
    const int i = (blockIdx.x * 256 + threadIdx.x) * 8;
    *(bf16x8*)(xb + i) = pack8(xf + i);
}

// ---------------- routing ----------------
__global__ __launch_bounds__(256) void route_kernel(
    const float* __restrict__ logits,   // [256][16]
    const int* __restrict__ topk_ptr,
    int* __restrict__ counts, int* __restrict__ tokens,
    int* __restrict__ tok_e, int* __restrict__ tok_slot, float* __restrict__ tok_wt)
{
    __shared__ int lds_counts[N_EXP];
    const int t = threadIdx.x;
    if (t < N_EXP) lds_counts[t] = 0;
    __syncthreads();

    int K = topk_ptr[0];
    if (K > 8) K = 8;
    if (K < 1) K = 1;

    float l[N_EXP];
    #pragma unroll
    for (int j = 0; j < N_EXP; ++j) l[j] = logits[t * N_EXP + j];

    float M = l[0];
    #pragma unroll
    for (int j = 1; j < N_EXP; ++j) M = fmaxf(M, l[j]);

    int idx[8]; float lv[8]; unsigned used = 0u;
    for (int k = 0; k < K; ++k) {
        int bi = 0; float bv = -1e30f;
        #pragma unroll
        for (int j = 0; j < N_EXP; ++j)
            if (!((used >> j) & 1u) && l[j] > bv) { bv = l[j]; bi = j; }
        used |= 1u << bi;
        idx[k] = bi; lv[k] = bv;
    }
    float w[8], s = 0.f;
    for (int k = 0; k < K; ++k) { w[k] = __expf(lv[k] - M); s += w[k]; }
    const float inv = 1.0f / s;

    for (int k = 0; k < K; ++k) {
        const int e = idx[k];
        const int slot = atomicAdd(&lds_counts[e], 1);
        tokens[e * MAX_SLOTS + slot] = t;
        tok_e[t * 8 + k] = e; tok_slot[t * 8 + k] = slot; tok_wt[t * 8 + k] = w[k] * inv;
    }
    __syncthreads();
    if (t < N_EXP) counts[t] = lds_counts[t];
}

// ---------------- GEMM1: wave computes NT m-tiles of one 16-wide i-tile ----------------
template <int NT>
__device__ __forceinline__ void gemm1_tiles(
    const short* __restrict__ xb, const float* __restrict__ wg, const float* __restrict__ wu,
    const int* __restrict__ toks, short* __restrict__ act,
    const int e, const int i_base, const int wave, const int nl, const int quad,
    const int count)
{
    const short* xr[NT];
    #pragma unroll
    for (int j = 0; j < NT; ++j) {
        int s = (wave + 4 * j) * 16 + nl;
        if (s >= count) s = count - 1;      // clamped rows dropped at store
        xr[j] = xb + (size_t)toks[s] * H_DIM;
    }
    floatx4 ag[NT], au[NT];
    #pragma unroll
    for (int j = 0; j < NT; ++j) { ag[j] = (floatx4)0.0f; au[j] = (floatx4)0.0f; }

    #pragma unroll 2
    for (int k = 0; k < H_DIM; k += 32) {
        const int ko = k + quad * 8;
        bf16x8 bg = pack8(wg + ko);
        bf16x8 bu = pack8(wu + ko);
        #pragma unroll
        for (int j = 0; j < NT; ++j) {
            bf16x8 a = *(const bf16x8*)(xr[j] + ko);
            ag[j] = __builtin_amdgcn_mfma_f32_16x16x32_bf16(a, bg, ag[j], 0, 0, 0);
            au[j] = __builtin_amdgcn_mfma_f32_16x16x32_bf16(a, bu, au[j], 0, 0, 0);
        }
    }
    #pragma unroll
    for (int j = 0; j < NT; ++j) {
        #pragma unroll
        for (int r = 0; r < 4; ++r) {
            const int slot = (wave + 4 * j) * 16 + quad * 4 + r;  // D: row=quad*4+r, col=nl
            if (slot < count) {
                const float g = ag[j][r], u = au[j][r];
                const float a = g / (1.0f + __expf(-g)) * u;      // silu(g)*u
                act[(size_t)(e * MAX_SLOTS + slot) * I_DIM + i_base + nl] = f2bf(a);
            }
        }
    }
}

__global__ __launch_bounds__(256, 4) void gemm1_kernel(
    const short* __restrict__ xb,     // [256][2048] bf16
    const float* __restrict__ w1,     // [16][2048][2048] fp32
    const int* __restrict__ counts, const int* __restrict__ tokens,
    short* __restrict__ act)          // [16][256][1024] bf16
{
    const int e = blockIdx.x;
    const int count = counts[e];
    if (count == 0) return;
    const int wave = (int)(threadIdx.x >> 6), lane = (int)(threadIdx.x & 63);
    const int nl = lane & 15, quad = lane >> 4;
    const int i_base = blockIdx.y * 16;                 // grid.y = 64
    const int ntiles = (count + 15) >> 4;               // <= 16
    if (wave >= ntiles) return;
    const int nown = (ntiles - wave + 3) >> 2;          // 1..4

    const float* wg = w1 + ((size_t)e * H_DIM + (i_base + nl)) * H_DIM;
    const float* wu = w1 + ((size_t)e * H_DIM + (I_DIM + i_base + nl)) * H_DIM;
    const int* toks = tokens + e * MAX_SLOTS;

    if      (nown == 1) gemm1_tiles<1>(xb, wg, wu, toks, act, e, i_base, wave, nl, quad, count);
    else if (nown == 2) gemm1_tiles<2>(xb, wg, wu, toks, act, e, i_base, wave, nl, quad, count);
    else if (nown == 3) gemm1_tiles<3>(xb, wg, wu, toks, act, e, i_base, wave, nl, quad, count);
    else                gemm1_tiles<4>(xb, wg, wu, toks, act, e, i_base, wave, nl, quad, count);
}

// ---------------- GEMM2: y = act_e @ w2[e]^T ----------------
template <int NT>
__device__ __forceinline__ void gemm2_tiles(
    const short* __restrict__ acte, const float* __restrict__ wr,
    short* __restrict__ y,
    const int e, const int h_base, const int wave, const int nl, const int quad,
    const int count)
{
    const short* ar[NT];
    #pragma unroll
    for (int j = 0; j < NT; ++j) {
        int s = (wave + 4 * j) * 16 + nl;
        if (s >= count) s = count - 1;
        ar[j] = acte + (size_t)s * I_DIM;
    }
    floatx4 acc[NT];
    #pragma unroll
    for (int j = 0; j < NT; ++j) acc[j] = (floatx4)0.0f;

    #pragma unroll 2
    for (int k = 0; k < I_DIM; k += 32) {
        const int ko = k + quad * 8;
        bf16x8 b = pack8(wr + ko);
        #pragma unroll
        for (int j = 0; j < NT; ++j) {
            bf16x8 a = *(const bf16x8*)(ar[j] + ko);
            acc[j] = __builtin_amdgcn_mfma_f32_16x16x32_bf16(a, b, acc[j], 0, 0, 0);
        }
    }
    #pragma unroll
    for (int j = 0; j < NT; ++j) {
        #pragma unroll
        for (int r = 0; r < 4; ++r) {
            const int slot = (wave + 4 * j) * 16 + quad * 4 + r;
            if (slot < count)
                y[(size_t)(e * MAX_SLOTS + slot) * H_DIM + h_base + nl] = f2bf(acc[j][r]);
        }
    }
}

__global__ __launch_bounds__(256, 4) void gemm2_kernel(
    const short* __restrict__ act,    // [16][256][1024] bf16
    const float* __restrict__ w2,     // [16][2048][1024] fp32
    const int* __restrict__ counts,
    short* __restrict__ y)            // [16][256][2048] bf16
{
    const int e = blockIdx.x;
    const int count = counts[e];
    if (count == 0) return;
    const int wave = (int)(threadIdx.x >> 6), lane = (int)(threadIdx.x & 63);
    const int nl = lane & 15, quad = lane >> 4;
    const int h_base = blockIdx.y * 16;                 // grid.y = 128
    const int ntiles = (count + 15) >> 4;
    if (wave >= ntiles) return;
    const int nown = (ntiles - wave + 3) >> 2;

    const float* wr = w2 + ((size_t)e * H_DIM + h_base + nl) * I_DIM;
    const short* acte = act + (size_t)e * MAX_SLOTS * I_DIM;

    if      (nown == 1) gemm2_tiles<1>(acte, wr, y, e, h_base, wave, nl, quad, count);
    else if (nown == 2) gemm2_tiles<2>(acte, wr, y, e, h_base, wave, nl, quad, count);
    else if (nown == 3) gemm2_tiles<3>(acte, wr, y, e, h_base, wave, nl, quad, count);
    else                gemm2_tiles<4>(acte, wr, y, e, h_base, wave, nl, quad, count);
}

// ---------------- gather: out[t][h] = sum_k wt * y[e_k][slot_k][h] (fp32) ----------------
__global__ __launch_bounds__(256) void gather_kernel(
    const short* __restrict__ y, const int* __restrict__ topk_ptr,
    const int* __restrict__ tok_e, const int* __restrict__ tok_slot,
    const float* __restrict__ tok_wt, float* __restrict__ out)
{
    const int t = blockIdx.x;
    int K = topk_ptr[0];
    if (K > 8) K = 8;
    if (K < 1) K = 1;
    int e[8], sl[8]; float w[8];
    for (int k = 0; k < K; ++k) {
        e[k] = tok_e[t * 8 + k]; sl[k] = tok_slot[t * 8 + k]; w[k] = tok_wt[t * 8 + k];
    }
    for (int h = threadIdx.x; h < H_DIM; h += 256) {
        float s = 0.f;
        for (int k = 0; k < K; ++k)
            s += w[k] * bf2f(y[(size_t)(e[k] * MAX_SLOTS + sl[k]) * H_DIM + h]);
        out[(size_t)t * H_DIM + h] = s;
    }
}

// ---------------- launch ----------------
extern "C" void kernel_launch(void* const* d_in, const int* in_sizes, int n_in,
                              void* d_out, int out_size, void* d_ws, size_t ws_size,
                              hipStream_t stream)
{
    const float* x  = (const float*)d_in[0];
    const float* rl = (const float*)d_in[1];
    const float* w1 = (const float*)d_in[2];
    const float* w2 = (const float*)d_in[3];
    const int* topk = (const int*)d_in[4];

    char* ws = (char*)d_ws;
    int*   counts   = (int*)  (ws + 0);          //   64 B
    int*   tokens   = (int*)  (ws + 256);        //  16 KB [16][256]
    int*   tok_e    = (int*)  (ws + 16640);      //   8 KB [256][8]
    int*   tok_slot = (int*)  (ws + 24832);      //   8 KB
    float* tok_wt   = (float*)(ws + 33024);      //   8 KB
    short* xb       = (short*)(ws + 65536);      //   1 MB [256][2048] bf16
    short* act      = (short*)(ws + 1114112);    //   8 MB [16][256][1024] bf16
    short* yb       = (short*)(ws + 9502720);    //  16 MB [16][256][2048] bf16

    convert_x_kernel<<<256, 256, 0, stream>>>(x, xb);
    route_kernel<<<1, 256, 0, stream>>>(rl, topk, counts, tokens, tok_e, tok_slot, tok_wt);
    gemm1_kernel<<<dim3(N_EXP, 64), 256, 0, stream>>>(xb, w1, counts, tokens, act);
    gemm2_kernel<<<dim3(N_EXP, 128), 256, 0, stream>>>(act, w2, counts, yb);
    gather_kernel<<<T_TOK, 256, 0, stream>>>(yb, topk, tok_e, tok_slot, tok_wt, (float*)d_out);
}